// Round 11
// baseline (556.688 us; speedup 1.0000x reference)
//
#include <hip/hip_runtime.h>
#include <stdint.h>

// ---------------------------------------------------------------------------
// VQVAE-with-attention forward, MI355X (gfx950).
// bf16 GEMMs: 128x128 tile, BK=64, 2x2 waves, mfma_f32_32x32x16_bf16
// (16 MFMA x 8cyc vs 32 x 5cyc per K-step), 32 KB LDS, zero-conflict XOR
// swizzle, launch_bounds(256,4). z-GEMM fuses fp8 output (MODE 5).
// dist GEMM: exact r7 kernel (fp8 16x16x32, BK=128, 176 us proven).
// Decoder: out = CBout[idx] LUT on the 8192 codebook rows.
// History: r8 mfma_scale spilled (refuted); r9 BK=256 halved residency
// (refuted); 1.678e7 "bank conflicts" in dist8 = argmin shfl epilogue.
// ---------------------------------------------------------------------------

typedef unsigned short u16;
typedef unsigned char u8;
typedef __attribute__((ext_vector_type(8))) short short8;
typedef __attribute__((ext_vector_type(4))) float f32x4;
typedef __attribute__((ext_vector_type(16))) float f32x16;

#define B_SZ 16384
#define DIN 1280
#define DH 1024
#define DE 512
#define KCB 8192

#define BM 128
#define BN 128
#define BK 64

__device__ __forceinline__ float bf2f(u16 u) {
  union { unsigned int u; float f; } v; v.u = ((unsigned int)u) << 16; return v.f;
}
__device__ __forceinline__ u16 f2bf(float f) {
  union { float f; unsigned int u; } v; v.f = f;
  unsigned int r = v.u + 0x7FFFu + ((v.u >> 16) & 1u);  // RNE
  return (u16)(r >> 16);
}
// f32 -> fp8 e4m3fn (OCP): saturating, RNE. bit layout s[7] e[6:3] m[2:0], bias 7.
__device__ __forceinline__ u8 f2e4m3(float f) {
  union { float f; unsigned int u; } v; v.f = f;
  unsigned int s = (v.u >> 24) & 0x80u;
  v.u &= 0x7fffffffu;
  if (v.f >= 448.0f) return (u8)(s | 0x7e);
  if (v.f < 0.0009765625f) return (u8)s;            // < 2^-10 -> 0
  if (v.f < 0.015625f) {                            // subnormal, quantum 2^-9
    int q = (int)(v.f * 512.0f + 0.5f);             // 1..8 (8 rolls into 2^-6)
    return (u8)(s | q);
  }
  unsigned int r = v.u + 0x7ffffu + ((v.u >> 20) & 1u);
  int e = (int)((r >> 23) & 255u) - 127 + 7;
  if (e >= 16) return (u8)(s | 0x7e);
  unsigned int m = (r >> 20) & 7u;
  return (u8)(s | ((unsigned int)e << 3) | m);
}
__device__ __forceinline__ float e4m32f(u8 b) {
  int e = (b >> 3) & 15, m = b & 7;
  float v = (e == 0) ? (m * 0.001953125f) : ldexpf((float)(8 + m), e - 10);
  return (b & 0x80) ? -v : v;
}
__device__ __forceinline__ void async16(const void* g, void* l) {
  __builtin_amdgcn_global_load_lds((__attribute__((address_space(1))) void*)(g),
                                   (__attribute__((address_space(3))) void*)(l),
                                   16, 0, 0);
}
__device__ __forceinline__ float wave_sum(float s) {
  #pragma unroll
  for (int m = 1; m < 64; m <<= 1) s += __shfl_xor(s, m, 64);
  return s;
}

// f32 -> bf16 conversion, 4 elems/thread
__global__ __launch_bounds__(256) void k_f2bf(const float* __restrict__ in,
                                              u16* __restrict__ out, int n) {
  int i = (blockIdx.x * 256 + threadIdx.x) * 4;
  if (i < n) {
    float4 v = *(const float4*)(in + i);
    ushort4 o;
    o.x = f2bf(v.x); o.y = f2bf(v.y); o.z = f2bf(v.z); o.w = f2bf(v.w);
    *(ushort4*)(out + i) = o;
  }
}

// codebook f32 -> fp8(x 2^20) + effective norms (alpha/beta * ||c_hat||^2)
__global__ __launch_bounds__(256) void k_cvt_cb8(const float* __restrict__ cb,
                                                 u8* __restrict__ c8,
                                                 float* __restrict__ cnE) {
  int row = blockIdx.x * 4 + (threadIdx.x >> 6);
  int lane = threadIdx.x & 63;
  const float* r = cb + (size_t)row * DE + lane * 8;
  u8 o[8];
  float s = 0.f;
  #pragma unroll
  for (int j = 0; j < 8; ++j) {
    float f = r[j] * 1048576.0f;   // 2^20
    u8 q = f2e4m3(f);
    o[j] = q;
    float dq = e4m32f(q);
    s += dq * dq;
  }
  *(uint2*)(c8 + (size_t)row * DE + lane * 8) = *(uint2*)o;
  s = wave_sum(s);
  if (lane == 0) cnE[row] = s * (1.0f / 65536.0f);  // alpha/beta = 2^-16
}

// w_v [1024x1024] f32 -> transposed bf16 (out[n][k] = w_v[k][n])
__global__ __launch_bounds__(256) void k_trans_bf(const float* __restrict__ in,
                                                  u16* __restrict__ out) {
  __shared__ float tt[32][33];
  int tx = threadIdx.x & 31, ty = threadIdx.x >> 5;  // ty 0..7
  int k0 = blockIdx.x * 32, n0 = blockIdx.y * 32;
  #pragma unroll
  for (int i = 0; i < 4; ++i)
    tt[ty + i * 8][tx] = in[(size_t)(k0 + ty + i * 8) * DH + n0 + tx];
  __syncthreads();
  #pragma unroll
  for (int i = 0; i < 4; ++i)
    out[(size_t)(n0 + ty + i * 8) * DH + k0 + tx] = f2bf(tt[tx][ty + i * 8]);
}

// b_vo = w_o @ b_v + b_o  (wave per row)
__global__ __launch_bounds__(256) void k_bvo(const float* __restrict__ w_o,
                                             const float* __restrict__ b_v,
                                             const float* __restrict__ b_o,
                                             float* __restrict__ bvo) {
  int row = blockIdx.x * 4 + (threadIdx.x >> 6);
  int lane = threadIdx.x & 63;
  const float* r = w_o + (size_t)row * DH;
  float s = 0.f;
  #pragma unroll
  for (int i = 0; i < DH / 64; ++i) s += r[lane + i * 64] * b_v[lane + i * 64];
  s = wave_sum(s);
  if (lane == 0) bvo[row] = b_o[row] + s;
}

// MODE: 0 bias->bf16, 1 bias+res->bf16, 2 bias+relu->bf16,
//       3 bias+relu+res->bf16, 4 bias+relu->f32, 5 bias->bf16 + fp8(x16)
template <int MODE>
__global__ __launch_bounds__(256, 4)
void k_gemm(const u16* __restrict__ A, const u16* __restrict__ W,
            const float* __restrict__ bias, const u16* __restrict__ Res,
            u16* __restrict__ O, float* __restrict__ Of,
            int N, int K, int nNB) {
  // A 128x64 + B 128x64 bf16 = 32 KB. Rows of 64 elems = 8 x 16B slots,
  // physical slot = logical ^ (row & 7). MFMA 32x32x16:
  //   A/B: row(col)=lane&31, k = 8*(lane>>5) + j  (one b128 per fragment)
  //   C/D: col=lane&31, row=(reg&3)+8*(reg>>2)+4*(lane>>5)
  __shared__ u16 sbuf[2 * 8192];
  const int tid = threadIdx.x;
  const int w = tid >> 6, lane = tid & 63;
  const int wm = w >> 1, wn = w & 1;     // 2 x 2 waves; wave tile 64 x 64
  const int l31 = lane & 31, lhi = lane >> 5;

  const int cpx = gridDim.x >> 3;
  const int lin = (blockIdx.x & 7) * cpx + (blockIdx.x >> 3);
  const int bm = lin / nNB, bn = lin % nNB;
  const int m0 = bm * BM, n0 = bn * BN;
  const int NT = K >> 6;

  const int srow = tid >> 3;
  const int sks = ((tid & 7) ^ (srow & 7)) * 8;
  const u16* gA = A + (size_t)(m0 + srow) * K + sks;
  const u16* gB = W + (size_t)(n0 + srow) * K + sks;
  const int K32 = K * 32;
  u16* const sT = sbuf + tid * 8;

  // read bases (elem units); rows m*32 apart share row&7 = l31&7
  const int ar0 = (wm * 64 + l31) * 64;
  const int ar1 = (wm * 64 + 32 + l31) * 64;
  const int br0 = 8192 + (wn * 64 + l31) * 64;
  const int br1 = 8192 + (wn * 64 + 32 + l31) * 64;
  const int r7 = l31 & 7;

  f32x16 acc[2][2];
  #pragma unroll
  for (int m = 0; m < 2; ++m)
    #pragma unroll
    for (int n = 0; n < 2; ++n)
      #pragma unroll
      for (int r = 0; r < 16; ++r) acc[m][n][r] = 0.f;

  for (int t = 0; t < NT; ++t) {
    #pragma unroll
    for (int i = 0; i < 4; ++i) async16(gA + i * K32, sT + i * 2048);
    #pragma unroll
    for (int i = 0; i < 4; ++i) async16(gB + i * K32, sT + 8192 + i * 2048);
    gA += 64; gB += 64;
    __syncthreads();
    #pragma unroll
    for (int ks = 0; ks < 4; ++ks) {      // k-steps of 16
      const int sl = (((ks * 2 + lhi) ^ r7) & 7) * 8;
      short8 a0 = *(const short8*)(sbuf + ar0 + sl);
      short8 a1 = *(const short8*)(sbuf + ar1 + sl);
      short8 b0 = *(const short8*)(sbuf + br0 + sl);
      short8 b1 = *(const short8*)(sbuf + br1 + sl);
      acc[0][0] = __builtin_amdgcn_mfma_f32_32x32x16_bf16(a0, b0, acc[0][0], 0, 0, 0);
      acc[0][1] = __builtin_amdgcn_mfma_f32_32x32x16_bf16(a0, b1, acc[0][1], 0, 0, 0);
      acc[1][0] = __builtin_amdgcn_mfma_f32_32x32x16_bf16(a1, b0, acc[1][0], 0, 0, 0);
      acc[1][1] = __builtin_amdgcn_mfma_f32_32x32x16_bf16(a1, b1, acc[1][1], 0, 0, 0);
    }
    __syncthreads();
  }

  u8* z8o = (u8*)Of;   // MODE 5 secondary output
  float bb[2];
  bb[0] = bias[n0 + wn * 64 + l31];
  bb[1] = bias[n0 + wn * 64 + 32 + l31];
  #pragma unroll
  for (int m = 0; m < 2; ++m) {
    #pragma unroll
    for (int n = 0; n < 2; ++n) {
      int gc = n0 + wn * 64 + n * 32 + l31;
      #pragma unroll
      for (int r = 0; r < 16; ++r) {
        int gr = m0 + wm * 64 + m * 32 + (r & 3) + 8 * (r >> 2) + 4 * lhi;
        float v = acc[m][n][r] + bb[n];
        if constexpr (MODE == 2 || MODE == 3 || MODE == 4) v = fmaxf(v, 0.f);
        if constexpr (MODE == 1 || MODE == 3) v += bf2f(Res[(size_t)gr * N + gc]);
        if constexpr (MODE == 4) {
          Of[(size_t)gr * N + gc] = v;
        } else {
          O[(size_t)gr * N + gc] = f2bf(v);
          if constexpr (MODE == 5) z8o[(size_t)gr * N + gc] = f2e4m3(v * 16.0f);
        }
      }
    }
  }
}

// fp8 distance-argmin GEMM (exact r7 kernel, 176 us proven):
// scores = cnE[c] - 2 * (z8 . c8), M=16384 N=8192 K=512 fp8, BK=128.
__global__ __launch_bounds__(256, 4)
void k_dist8(const u8* __restrict__ Z8, const u8* __restrict__ C8,
             const float* __restrict__ cnE,
             float* __restrict__ partv, int* __restrict__ parti) {
  __shared__ u8 sbuf[2 * 16384];   // A 128x128B + B 128x128B = 32 KB
  const int tid = threadIdx.x;
  const int w = tid >> 6, lane = tid & 63;
  const int wm = w >> 1, wn = w & 1;
  const int lr = lane & 15, lk = lane >> 4;
  const int nNB = KCB / 128;  // 64

  const int cpx = gridDim.x >> 3;
  const int lin = (blockIdx.x & 7) * cpx + (blockIdx.x >> 3);
  const int bm = lin / nNB, bn = lin % nNB;
  const int m0 = bm * 128, n0 = bn * 128;

  const int srow = tid >> 3;
  const int sko = ((tid & 7) ^ (srow & 7)) * 16;
  const u8* gA = Z8 + (size_t)(m0 + srow) * DE + sko;
  const u8* gB = C8 + (size_t)(n0 + srow) * DE + sko;
  u8* const sT = sbuf + tid * 16;

  const int arow = (wm * 64 + lr) * 128;
  const int brow = 16384 + (wn * 64 + lr) * 128;
  const int half8 = (lk & 1) * 8;
  const int swz = lr & 7;

  f32x4 acc[4][4];
  #pragma unroll
  for (int m = 0; m < 4; ++m)
    #pragma unroll
    for (int n = 0; n < 4; ++n) acc[m][n] = (f32x4){0.f, 0.f, 0.f, 0.f};

  for (int t = 0; t < 4; ++t) {   // 4 K-tiles of 128
    #pragma unroll
    for (int i = 0; i < 4; ++i) async16(gA + i * (32 * DE), sT + i * 4096);
    #pragma unroll
    for (int i = 0; i < 4; ++i) async16(gB + i * (32 * DE), sT + 16384 + i * 4096);
    gA += 128; gB += 128;
    __syncthreads();
    #pragma unroll
    for (int ks = 0; ks < 4; ++ks) {
      const int sl = (((2 * ks + (lk >> 1)) ^ swz) & 7) * 16 + half8;
      long af[4], bfr[4];
      #pragma unroll
      for (int m = 0; m < 4; ++m) af[m] = *(const long*)(sbuf + arow + m * 2048 + sl);
      #pragma unroll
      for (int n = 0; n < 4; ++n) bfr[n] = *(const long*)(sbuf + brow + n * 2048 + sl);
      #pragma unroll
      for (int m = 0; m < 4; ++m)
        #pragma unroll
        for (int n = 0; n < 4; ++n)
          acc[m][n] = __builtin_amdgcn_mfma_f32_16x16x32_fp8_fp8(af[m], bfr[n], acc[m][n], 0, 0, 0);
    }
    __syncthreads();
  }

  // argmin within this 128-col block
  float* sv = (float*)&sbuf[0];            // [2][128]
  int*   si = (int*)(sv + 2 * 128);
  float cn[4];
  int gcn[4];
  #pragma unroll
  for (int n = 0; n < 4; ++n) {
    gcn[n] = n0 + wn * 64 + n * 16 + lr;
    cn[n] = cnE[gcn[n]];
  }
  #pragma unroll
  for (int m = 0; m < 4; ++m) {
    #pragma unroll
    for (int j = 0; j < 4; ++j) {
      float bv = 3.0e38f; int bc = 0;
      #pragma unroll
      for (int n = 0; n < 4; ++n) {
        float v = cn[n] - 2.0f * acc[m][n][j];
        if (v < bv || (v == bv && gcn[n] < bc)) { bv = v; bc = gcn[n]; }
      }
      #pragma unroll
      for (int mask = 1; mask < 16; mask <<= 1) {
        float ov = __shfl_xor(bv, mask, 64);
        int oc = __shfl_xor(bc, mask, 64);
        if (ov < bv || (ov == bv && oc < bc)) { bv = ov; bc = oc; }
      }
      if (lr == 0) {
        int row = wm * 64 + m * 16 + lk * 4 + j;
        sv[wn * 128 + row] = bv; si[wn * 128 + row] = bc;
      }
    }
  }
  __syncthreads();
  if (tid < 128) {
    float v = sv[tid]; int ii = si[tid];
    float ov = sv[128 + tid]; int oi = si[128 + tid];
    if (ov < v || (ov == v && oi < ii)) { v = ov; ii = oi; }
    partv[(size_t)(m0 + tid) * 64 + bn] = v;
    parti[(size_t)(m0 + tid) * 64 + bn] = ii;
  }
}

// LayerNorm over DH=1024, wave per row, 16 elems/lane
__global__ __launch_bounds__(256)
void k_ln(const u16* __restrict__ X, const float* __restrict__ g,
          const float* __restrict__ b, u16* __restrict__ O) {
  int row = blockIdx.x * 4 + (threadIdx.x >> 6);
  int lane = threadIdx.x & 63;
  const u16* xr = X + (size_t)row * DH + lane * 16;
  uint4 d0 = *(const uint4*)(xr);
  uint4 d1 = *(const uint4*)(xr + 8);
  unsigned int ww[8] = {d0.x, d0.y, d0.z, d0.w, d1.x, d1.y, d1.z, d1.w};
  float v[16];
  #pragma unroll
  for (int i = 0; i < 8; ++i) {
    v[2 * i] = bf2f((u16)(ww[i] & 0xffff));
    v[2 * i + 1] = bf2f((u16)(ww[i] >> 16));
  }
  float s = 0.f;
  #pragma unroll
  for (int i = 0; i < 16; ++i) s += v[i];
  s = wave_sum(s);
  float mean = s * (1.0f / DH);
  float q = 0.f;
  #pragma unroll
  for (int i = 0; i < 16; ++i) { float d = v[i] - mean; q += d * d; }
  q = wave_sum(q);
  float rstd = rsqrtf(q * (1.0f / DH) + 1e-5f);
  int base = lane * 16;
  unsigned int ow[8];
  #pragma unroll
  for (int i = 0; i < 8; ++i) {
    float a0 = (v[2 * i] - mean) * rstd * g[base + 2 * i] + b[base + 2 * i];
    float a1 = (v[2 * i + 1] - mean) * rstd * g[base + 2 * i + 1] + b[base + 2 * i + 1];
    ow[i] = (unsigned int)f2bf(a0) | ((unsigned int)f2bf(a1) << 16);
  }
  uint4 o0 = {ow[0], ow[1], ow[2], ow[3]};
  uint4 o1 = {ow[4], ow[5], ow[6], ow[7]};
  *(uint4*)(O + (size_t)row * DH + lane * 16) = o0;
  *(uint4*)(O + (size_t)row * DH + lane * 16 + 8) = o1;
}

// final argmin over 64 partials/row; per-row loss + idx (no quant write)
__global__ __launch_bounds__(256)
void k_argmin_fin(const float* __restrict__ partv, const int* __restrict__ parti,
                  const float* __restrict__ cb, const u16* __restrict__ zq,
                  float* __restrict__ lossbuf, int* __restrict__ idxbuf) {
  int row = blockIdx.x * 4 + (threadIdx.x >> 6);
  int lane = threadIdx.x & 63;
  float v = partv[(size_t)row * 64 + lane];
  int idx = parti[(size_t)row * 64 + lane];
  #pragma unroll
  for (int m = 1; m < 64; m <<= 1) {
    float ov = __shfl_xor(v, m, 64);
    int oi = __shfl_xor(idx, m, 64);
    if (ov < v || (ov == v && oi < idx)) { v = ov; idx = oi; }
  }
  const float* cr = cb + (size_t)idx * DE;
  const u16* zr = zq + (size_t)row * DE;
  float s = 0.f;
  #pragma unroll
  for (int i = 0; i < DE / 64; ++i) {
    int e = lane + i * 64;
    float d = cr[e] - bf2f(zr[e]);
    s += d * d;
  }
  s = wave_sum(s);
  if (lane == 0) { lossbuf[row] = s; idxbuf[row] = idx; }
}

// out[i] = CBout[idx[i]]  (wave per row; 1280 f32 = 64 lanes x 5 float4)
__global__ __launch_bounds__(256)
void k_gather(const int* __restrict__ idxbuf, const float* __restrict__ tab,
              float* __restrict__ out) {
  int row = blockIdx.x * 4 + (threadIdx.x >> 6);
  int lane = threadIdx.x & 63;
  const float* src = tab + (size_t)idxbuf[row] * DIN;
  float* dst = out + (size_t)row * DIN;
  #pragma unroll
  for (int j = 0; j < 5; ++j) {
    int e = (lane + j * 64) * 4;
    *(float4*)(dst + e) = *(const float4*)(src + e);
  }
}

// single-block reduction of B_SZ per-row losses -> scaled scalar
__global__ __launch_bounds__(256)
void k_fin(const float* __restrict__ lossbuf, float* __restrict__ out) {
  float s = 0.f;
  for (int i = threadIdx.x; i < B_SZ; i += 256) s += lossbuf[i];
  s = wave_sum(s);
  __shared__ float sm[4];
  if ((threadIdx.x & 63) == 0) sm[threadIdx.x >> 6] = s;
  __syncthreads();
  if (threadIdx.x == 0)
    out[0] = 1.25f * (sm[0] + sm[1] + sm[2] + sm[3]) *
             (1.0f / ((float)B_SZ * (float)DE));
}

extern "C" void kernel_launch(void* const* d_in, const int* in_sizes, int n_in,
                              void* d_out, int out_size, void* d_ws, size_t ws_size,
                              hipStream_t stream) {
  const float* x    = (const float*)d_in[0];
  const float* w_in = (const float*)d_in[1];
  const float* b_in = (const float*)d_in[2];
  const float* w_v  = (const float*)d_in[3];
  const float* b_v  = (const float*)d_in[4];
  const float* w_o  = (const float*)d_in[5];
  const float* b_o  = (const float*)d_in[6];
  const float* ln_g = (const float*)d_in[7];
  const float* ln_b = (const float*)d_in[8];
  const float* w1   = (const float*)d_in[9];
  const float* b1   = (const float*)d_in[10];
  const float* w2   = (const float*)d_in[11];
  const float* b2   = (const float*)d_in[12];
  const float* w_cb = (const float*)d_in[13];
  const float* b_cb = (const float*)d_in[14];
  const float* cb   = (const float*)d_in[15];
  const float* w_d1 = (const float*)d_in[16];
  const float* b_d1 = (const float*)d_in[17];
  const float* w_d2 = (const float*)d_in[18];
  const float* b_d2 = (const float*)d_in[19];
  (void)in_sizes; (void)n_in; (void)out_size; (void)ws_size;

  char* ws = (char*)d_ws;
  size_t off = 0;
  auto alloc = [&](size_t n) {
    char* p = ws + off;
    off += (n + 255) & ~(size_t)255;
    return p;
  };
  u16* x_bf = (u16*)alloc((size_t)B_SZ * DIN * 2);  // dead after h0
  u16* winb = (u16*)alloc((size_t)DH * DIN * 2);
  u16* wob  = (u16*)alloc((size_t)DH * DH * 2);
  u16* w1b  = (u16*)alloc((size_t)DH * DH * 2);
  u16* w2b  = (u16*)alloc((size_t)DH * DH * 2);
  u16* wcbb = (u16*)alloc((size_t)DE * DH * 2);
  u16* wd1b = (u16*)alloc((size_t)DH * DE * 2);
  u16* wd2b = (u16*)alloc((size_t)DIN * DH * 2);
  u16* wvob = (u16*)alloc((size_t)DH * DH * 2);     // fused W_vo (bf16)
  u8*  cb8  = (u8*)alloc((size_t)KCB * DE);
  float* cnormE = (float*)alloc((size_t)KCB * 4);
  float* bvo    = (float*)alloc((size_t)DH * 4);
  float* zero4k = (float*)alloc((size_t)DH * 4);
  float* lossbuf = (float*)alloc((size_t)B_SZ * 4);
  u16* S1 = (u16*)alloc((size_t)B_SZ * DH * 2);
  u16* S2 = (u16*)alloc((size_t)B_SZ * DH * 2);
  u16* S3 = (u16*)alloc((size_t)B_SZ * DH * 2);
  u16* zq = (u16*)alloc((size_t)B_SZ * DE * 2);   // z (kept for loss)
  float* partv = (float*)alloc((size_t)B_SZ * 64 * 4);
  int*   parti = (int*)alloc((size_t)B_SZ * 64 * 4);
  u16* cbbf = (u16*)alloc((size_t)KCB * DE * 2);  // codebook bf16
  int* idxbuf = (int*)alloc((size_t)B_SZ * 4);
  u16* wvtb = S3;                 // transposed w_v (bf16), dead before S3 written
  u8*  z8   = (u8*)S2;            // fp8 z; S2 dead when written, dead before CBout
  u16* CBd1 = S1;                 // [8192x1024] bf16; S1 dead after mlp2
  float* CBout = (float*)S2;      // [8192x1280] f32 = 42 MB, spans S2+S3

  dim3 blk(256);
  auto cvt = [&](const float* s, u16* d, int n) {
    k_f2bf<<<dim3(n / 1024), blk, 0, stream>>>(s, d, n);
  };
  cvt(x, x_bf, B_SZ * DIN);
  cvt(w_in, winb, DH * DIN);
  cvt(w_o, wob, DH * DH);
  cvt(w1, w1b, DH * DH);
  cvt(w2, w2b, DH * DH);
  cvt(w_cb, wcbb, DE * DH);
  cvt(w_d1, wd1b, DH * DE);
  cvt(w_d2, wd2b, DIN * DH);
  cvt(cb, cbbf, KCB * DE);
  k_trans_bf<<<dim3(32, 32), blk, 0, stream>>>(w_v, wvtb);
  k_bvo<<<dim3(DH / 4), blk, 0, stream>>>(w_o, b_v, b_o, bvo);
  k_cvt_cb8<<<dim3(KCB / 4), blk, 0, stream>>>(cb, cb8, cnormE);
  hipMemsetAsync(zero4k, 0, DH * 4, stream);

#define GG(M, N) dim3(((M) / BM) * ((N) / BN))
  // W_vo = w_o @ w_v  (A = w_o, W[n,k] = w_v[k,n])
  k_gemm<0><<<GG(DH, DH), blk, 0, stream>>>(wob, wvtb, zero4k, nullptr, wvob, nullptr,
                                            DH, DH, DH / BN);
  // h0 = x@w_in^T + b_in
  k_gemm<0><<<GG(B_SZ, DH), blk, 0, stream>>>(x_bf, winb, b_in, nullptr, S1, nullptr,
                                              DH, DIN, DH / BN);
  // attn + h0 = h0@W_vo^T + b_vo + h0
  k_gemm<1><<<GG(B_SZ, DH), blk, 0, stream>>>(S1, wvob, bvo, S1, S3, nullptr,
                                              DH, DH, DH / BN);
  // h1 = LN(attn+h0)
  k_ln<<<dim3(B_SZ / 4), blk, 0, stream>>>(S3, ln_g, ln_b, S1);
  // t = relu(h1@w1^T + b1)
  k_gemm<2><<<GG(B_SZ, DH), blk, 0, stream>>>(S1, w1b, b1, nullptr, S2, nullptr,
                                              DH, DH, DH / BN);
  // h2 = relu(t@w2^T + b2) + h1
  k_gemm<3><<<GG(B_SZ, DH), blk, 0, stream>>>(S2, w2b, b2, S1, S3, nullptr,
                                              DH, DH, DH / BN);
  // z = h2@w_cb^T + b_cb  -> zq (bf16) + z8 (fp8 x16, fused)
  k_gemm<5><<<GG(B_SZ, DE), blk, 0, stream>>>(S3, wcbb, b_cb, nullptr, zq, (float*)z8,
                                              DE, DH, DE / BN);
  // fp8 distance partials (r7 kernel)
  k_dist8<<<dim3((B_SZ / 128) * (KCB / 128)), blk, 0, stream>>>(z8, cb8, cnormE,
                                                                partv, parti);
  // final argmin + per-row loss + idx
  k_argmin_fin<<<dim3(B_SZ / 4), blk, 0, stream>>>(partv, parti, cb, zq,
                                                   lossbuf, idxbuf);
  // decoder lookup tables on the 8192 codebook rows:
  // CBd1 = relu(cb@w_d1^T + b_d1)   [8192x1024] bf16 (into S1)
  k_gemm<2><<<GG(KCB, DH), blk, 0, stream>>>(cbbf, wd1b, b_d1, nullptr, CBd1, nullptr,
                                             DH, DE, DH / BN);
  // CBout = relu(CBd1@w_d2^T + b_d2) [8192x1280] f32 (into S2+S3)
  k_gemm<4><<<GG(KCB, DIN), blk, 0, stream>>>(CBd1, wd2b, b_d2, nullptr, nullptr,
                                              CBout, DIN, DH, DIN / BN);
  // out = CBout[idx]
  k_gather<<<dim3(B_SZ / 4), blk, 0, stream>>>(idxbuf, CBout, (float*)d_out);
  // loss scalar at d_out[B*DIN]
  k_fin<<<dim3(1), blk, 0, stream>>>(lossbuf, ((float*)d_out) + (size_t)B_SZ * DIN);
#undef GG
}

// Round 12
// 525.282 us; speedup vs baseline: 1.0598x; 1.0598x over previous
//
#include <hip/hip_runtime.h>
#include <stdint.h>

// ---------------------------------------------------------------------------
// VQVAE-with-attention forward, MI355X (gfx950).  (r10 config restored)
// bf16 GEMMs: r5 structure (128x128, BK=64, 2x2 waves, mfma 16x16x32,
// 32 KB LDS, zero-conflict XOR swizzle), launch_bounds(256,4).
// dist GEMM: exact r7 kernel (fp8 16x16x32, BK=128, 176 us proven).
// Decoder: out = CBout[idx] LUT on the 8192 codebook rows.
// New: single batched f32->bf16 conversion kernel (8 dispatches -> 1).
// Refuted: r2/r4 deep pipelines (residency loss), r8 mfma_scale (spill),
// r9 BK=256 (residency), r11 mfma 32x32 (ILP loss in 2-barrier loop).
// ---------------------------------------------------------------------------

typedef unsigned short u16;
typedef unsigned char u8;
typedef __attribute__((ext_vector_type(8))) short short8;
typedef __attribute__((ext_vector_type(4))) float f32x4;

#define B_SZ 16384
#define DIN 1280
#define DH 1024
#define DE 512
#define KCB 8192

#define BM 128
#define BN 128
#define BK 64

__device__ __forceinline__ float bf2f(u16 u) {
  union { unsigned int u; float f; } v; v.u = ((unsigned int)u) << 16; return v.f;
}
__device__ __forceinline__ u16 f2bf(float f) {
  union { float f; unsigned int u; } v; v.f = f;
  unsigned int r = v.u + 0x7FFFu + ((v.u >> 16) & 1u);  // RNE
  return (u16)(r >> 16);
}
// f32 -> fp8 e4m3fn (OCP): saturating, RNE. bit layout s[7] e[6:3] m[2:0], bias 7.
__device__ __forceinline__ u8 f2e4m3(float f) {
  union { float f; unsigned int u; } v; v.f = f;
  unsigned int s = (v.u >> 24) & 0x80u;
  v.u &= 0x7fffffffu;
  if (v.f >= 448.0f) return (u8)(s | 0x7e);
  if (v.f < 0.0009765625f) return (u8)s;            // < 2^-10 -> 0
  if (v.f < 0.015625f) {                            // subnormal, quantum 2^-9
    int q = (int)(v.f * 512.0f + 0.5f);             // 1..8 (8 rolls into 2^-6)
    return (u8)(s | q);
  }
  unsigned int r = v.u + 0x7ffffu + ((v.u >> 20) & 1u);
  int e = (int)((r >> 23) & 255u) - 127 + 7;
  if (e >= 16) return (u8)(s | 0x7e);
  unsigned int m = (r >> 20) & 7u;
  return (u8)(s | ((unsigned int)e << 3) | m);
}
__device__ __forceinline__ float e4m32f(u8 b) {
  int e = (b >> 3) & 15, m = b & 7;
  float v = (e == 0) ? (m * 0.001953125f) : ldexpf((float)(8 + m), e - 10);
  return (b & 0x80) ? -v : v;
}
__device__ __forceinline__ void async16(const void* g, void* l) {
  __builtin_amdgcn_global_load_lds((__attribute__((address_space(1))) void*)(g),
                                   (__attribute__((address_space(3))) void*)(l),
                                   16, 0, 0);
}
__device__ __forceinline__ float wave_sum(float s) {
  #pragma unroll
  for (int m = 1; m < 64; m <<= 1) s += __shfl_xor(s, m, 64);
  return s;
}

// f32 -> bf16 conversion, 4 elems/thread (large single arrays: x)
__global__ __launch_bounds__(256) void k_f2bf(const float* __restrict__ in,
                                              u16* __restrict__ out, int n) {
  int i = (blockIdx.x * 256 + threadIdx.x) * 4;
  if (i < n) {
    float4 v = *(const float4*)(in + i);
    ushort4 o;
    o.x = f2bf(v.x); o.y = f2bf(v.y); o.z = f2bf(v.z); o.w = f2bf(v.w);
    *(ushort4*)(out + i) = o;
  }
}

// batched f32 -> bf16 over up to 8 segments (all sizes multiples of 1024)
struct CvtArgs {
  const float* src[8];
  u16* dst[8];
  int cum[9];   // cumulative block counts, cum[0] = 0
};
__global__ __launch_bounds__(256) void k_f2bf_multi(CvtArgs a) {
  int b = blockIdx.x;
  int s = 0;
  #pragma unroll
  for (int k = 0; k < 7; ++k) s += (b >= a.cum[s + 1]) ? 1 : 0;
  int i = ((b - a.cum[s]) * 256 + threadIdx.x) * 4;
  float4 v = *(const float4*)(a.src[s] + i);
  ushort4 o;
  o.x = f2bf(v.x); o.y = f2bf(v.y); o.z = f2bf(v.z); o.w = f2bf(v.w);
  *(ushort4*)(a.dst[s] + i) = o;
}

// codebook f32 -> fp8(x 2^20) + effective norms (alpha/beta * ||c_hat||^2)
__global__ __launch_bounds__(256) void k_cvt_cb8(const float* __restrict__ cb,
                                                 u8* __restrict__ c8,
                                                 float* __restrict__ cnE) {
  int row = blockIdx.x * 4 + (threadIdx.x >> 6);
  int lane = threadIdx.x & 63;
  const float* r = cb + (size_t)row * DE + lane * 8;
  u8 o[8];
  float s = 0.f;
  #pragma unroll
  for (int j = 0; j < 8; ++j) {
    float f = r[j] * 1048576.0f;   // 2^20
    u8 q = f2e4m3(f);
    o[j] = q;
    float dq = e4m32f(q);
    s += dq * dq;
  }
  *(uint2*)(c8 + (size_t)row * DE + lane * 8) = *(uint2*)o;
  s = wave_sum(s);
  if (lane == 0) cnE[row] = s * (1.0f / 65536.0f);  // alpha/beta = 2^-16
}

// z bf16 -> fp8(x 16), 8 elems/thread
__global__ __launch_bounds__(256) void k_z2fp8(const u16* __restrict__ in,
                                               u8* __restrict__ out) {
  int i = (blockIdx.x * 256 + threadIdx.x) * 8;
  uint4 d = *(const uint4*)(in + i);
  unsigned int ww[4] = {d.x, d.y, d.z, d.w};
  u8 o[8];
  #pragma unroll
  for (int j = 0; j < 4; ++j) {
    o[2 * j]     = f2e4m3(bf2f((u16)(ww[j] & 0xffff)) * 16.0f);
    o[2 * j + 1] = f2e4m3(bf2f((u16)(ww[j] >> 16)) * 16.0f);
  }
  *(uint2*)(out + i) = *(uint2*)o;
}

// w_v [1024x1024] f32 -> transposed bf16 (out[n][k] = w_v[k][n])
__global__ __launch_bounds__(256) void k_trans_bf(const float* __restrict__ in,
                                                  u16* __restrict__ out) {
  __shared__ float tt[32][33];
  int tx = threadIdx.x & 31, ty = threadIdx.x >> 5;  // ty 0..7
  int k0 = blockIdx.x * 32, n0 = blockIdx.y * 32;
  #pragma unroll
  for (int i = 0; i < 4; ++i)
    tt[ty + i * 8][tx] = in[(size_t)(k0 + ty + i * 8) * DH + n0 + tx];
  __syncthreads();
  #pragma unroll
  for (int i = 0; i < 4; ++i)
    out[(size_t)(n0 + ty + i * 8) * DH + k0 + tx] = f2bf(tt[tx][ty + i * 8]);
}

// b_vo = w_o @ b_v + b_o  (wave per row)
__global__ __launch_bounds__(256) void k_bvo(const float* __restrict__ w_o,
                                             const float* __restrict__ b_v,
                                             const float* __restrict__ b_o,
                                             float* __restrict__ bvo) {
  int row = blockIdx.x * 4 + (threadIdx.x >> 6);
  int lane = threadIdx.x & 63;
  const float* r = w_o + (size_t)row * DH;
  float s = 0.f;
  #pragma unroll
  for (int i = 0; i < DH / 64; ++i) s += r[lane + i * 64] * b_v[lane + i * 64];
  s = wave_sum(s);
  if (lane == 0) bvo[row] = b_o[row] + s;
}

// MODE: 0 bias->bf16, 1 bias+res->bf16, 2 bias+relu->bf16,
//       3 bias+relu+res->bf16, 4 bias+relu->f32
template <int MODE>
__global__ __launch_bounds__(256, 4)
void k_gemm(const u16* __restrict__ A, const u16* __restrict__ W,
            const float* __restrict__ bias, const u16* __restrict__ Res,
            u16* __restrict__ O, float* __restrict__ Of,
            int N, int K, int nNB) {
  // A 128x64 + B 128x64 bf16 = 32 KB. Rows of 64 elems = 8 x 16B slots,
  // physical slot = logical ^ (row & 7).
  __shared__ u16 sbuf[2 * 8192];
  const int tid = threadIdx.x;
  const int w = tid >> 6, lane = tid & 63;
  const int wm = w >> 1, wn = w & 1;     // 2 x 2 waves; wave tile 64 x 64
  const int lr = lane & 15, lk = lane >> 4;

  const int cpx = gridDim.x >> 3;
  const int lin = (blockIdx.x & 7) * cpx + (blockIdx.x >> 3);
  const int bm = lin / nNB, bn = lin % nNB;
  const int m0 = bm * BM, n0 = bn * BN;
  const int NT = K >> 6;

  const int srow = tid >> 3;
  const int sks = ((tid & 7) ^ (srow & 7)) * 8;
  const u16* gA = A + (size_t)(m0 + srow) * K + sks;
  const u16* gB = W + (size_t)(n0 + srow) * K + sks;
  const int K32 = K * 32;
  u16* const sT = sbuf + tid * 8;

  const int arow = (wm * 64 + lr) * 64;
  const int brow = 8192 + (wn * 64 + lr) * 64;
  const int sl0 = ((lk ^ (lr & 7)) & 7) * 8;
  const int sl1 = (((4 + lk) ^ (lr & 7)) & 7) * 8;

  f32x4 acc[4][4];
  #pragma unroll
  for (int m = 0; m < 4; ++m)
    #pragma unroll
    for (int n = 0; n < 4; ++n) acc[m][n] = (f32x4){0.f, 0.f, 0.f, 0.f};

  for (int t = 0; t < NT; ++t) {
    #pragma unroll
    for (int i = 0; i < 4; ++i) async16(gA + i * K32, sT + i * 2048);
    #pragma unroll
    for (int i = 0; i < 4; ++i) async16(gB + i * K32, sT + 8192 + i * 2048);
    gA += 64; gB += 64;
    __syncthreads();
    #pragma unroll
    for (int ks = 0; ks < 2; ++ks) {
      const int sl = ks ? sl1 : sl0;
      const u16* ab = sbuf + arow + sl;
      const u16* bb = sbuf + brow + sl;
      short8 af[4], bfr[4];
      #pragma unroll
      for (int m = 0; m < 4; ++m) af[m] = *(const short8*)(ab + m * 1024);
      #pragma unroll
      for (int n = 0; n < 4; ++n) bfr[n] = *(const short8*)(bb + n * 1024);
      #pragma unroll
      for (int m = 0; m < 4; ++m)
        #pragma unroll
        for (int n = 0; n < 4; ++n)
          acc[m][n] = __builtin_amdgcn_mfma_f32_16x16x32_bf16(af[m], bfr[n], acc[m][n], 0, 0, 0);
    }
    __syncthreads();
  }

  float bb4[4];
  #pragma unroll
  for (int n = 0; n < 4; ++n) bb4[n] = bias[n0 + wn * 64 + n * 16 + lr];
  #pragma unroll
  for (int m = 0; m < 4; ++m) {
    int gr = m0 + wm * 64 + m * 16 + lk * 4;
    #pragma unroll
    for (int n = 0; n < 4; ++n) {
      int gc = n0 + wn * 64 + n * 16 + lr;
      #pragma unroll
      for (int j = 0; j < 4; ++j) {
        float v = acc[m][n][j] + bb4[n];
        if constexpr (MODE == 2 || MODE == 3 || MODE == 4) v = fmaxf(v, 0.f);
        if constexpr (MODE == 1 || MODE == 3) v += bf2f(Res[(size_t)(gr + j) * N + gc]);
        if constexpr (MODE == 4) Of[(size_t)(gr + j) * N + gc] = v;
        else O[(size_t)(gr + j) * N + gc] = f2bf(v);
      }
    }
  }
}

// fp8 distance-argmin GEMM (exact r7 kernel, 176 us proven):
// scores = cnE[c] - 2 * (z8 . c8), M=16384 N=8192 K=512 fp8, BK=128.
__global__ __launch_bounds__(256, 4)
void k_dist8(const u8* __restrict__ Z8, const u8* __restrict__ C8,
             const float* __restrict__ cnE,
             float* __restrict__ partv, int* __restrict__ parti) {
  __shared__ u8 sbuf[2 * 16384];   // A 128x128B + B 128x128B = 32 KB
  const int tid = threadIdx.x;
  const int w = tid >> 6, lane = tid & 63;
  const int wm = w >> 1, wn = w & 1;
  const int lr = lane & 15, lk = lane >> 4;
  const int nNB = KCB / 128;  // 64

  const int cpx = gridDim.x >> 3;
  const int lin = (blockIdx.x & 7) * cpx + (blockIdx.x >> 3);
  const int bm = lin / nNB, bn = lin % nNB;
  const int m0 = bm * 128, n0 = bn * 128;

  const int srow = tid >> 3;
  const int sko = ((tid & 7) ^ (srow & 7)) * 16;
  const u8* gA = Z8 + (size_t)(m0 + srow) * DE + sko;
  const u8* gB = C8 + (size_t)(n0 + srow) * DE + sko;
  u8* const sT = sbuf + tid * 16;

  const int arow = (wm * 64 + lr) * 128;
  const int brow = 16384 + (wn * 64 + lr) * 128;
  const int half8 = (lk & 1) * 8;
  const int swz = lr & 7;

  f32x4 acc[4][4];
  #pragma unroll
  for (int m = 0; m < 4; ++m)
    #pragma unroll
    for (int n = 0; n < 4; ++n) acc[m][n] = (f32x4){0.f, 0.f, 0.f, 0.f};

  for (int t = 0; t < 4; ++t) {   // 4 K-tiles of 128
    #pragma unroll
    for (int i = 0; i < 4; ++i) async16(gA + i * (32 * DE), sT + i * 4096);
    #pragma unroll
    for (int i = 0; i < 4; ++i) async16(gB + i * (32 * DE), sT + 16384 + i * 4096);
    gA += 128; gB += 128;
    __syncthreads();
    #pragma unroll
    for (int ks = 0; ks < 4; ++ks) {
      const int sl = (((2 * ks + (lk >> 1)) ^ swz) & 7) * 16 + half8;
      long af[4], bfr[4];
      #pragma unroll
      for (int m = 0; m < 4; ++m) af[m] = *(const long*)(sbuf + arow + m * 2048 + sl);
      #pragma unroll
      for (int n = 0; n < 4; ++n) bfr[n] = *(const long*)(sbuf + brow + n * 2048 + sl);
      #pragma unroll
      for (int m = 0; m < 4; ++m)
        #pragma unroll
        for (int n = 0; n < 4; ++n)
          acc[m][n] = __builtin_amdgcn_mfma_f32_16x16x32_fp8_fp8(af[m], bfr[n], acc[m][n], 0, 0, 0);
    }
    __syncthreads();
  }

  // argmin within this 128-col block
  float* sv = (float*)&sbuf[0];            // [2][128]
  int*   si = (int*)(sv + 2 * 128);
  float cn[4];
  int gcn[4];
  #pragma unroll
  for (int n = 0; n < 4; ++n) {
    gcn[n] = n0 + wn * 64 + n * 16 + lr;
    cn[n] = cnE[gcn[n]];
  }
  #pragma unroll
  for (int m = 0; m < 4; ++m) {
    #pragma unroll
    for (int j = 0; j < 4; ++j) {
      float bv = 3.0e38f; int bc = 0;
      #pragma unroll
      for (int n = 0; n < 4; ++n) {
        float v = cn[n] - 2.0f * acc[m][n][j];
        if (v < bv || (v == bv && gcn[n] < bc)) { bv = v; bc = gcn[n]; }
      }
      #pragma unroll
      for (int mask = 1; mask < 16; mask <<= 1) {
        float ov = __shfl_xor(bv, mask, 64);
        int oc = __shfl_xor(bc, mask, 64);
        if (ov < bv || (ov == bv && oc < bc)) { bv = ov; bc = oc; }
      }
      if (lr == 0) {
        int row = wm * 64 + m * 16 + lk * 4 + j;
        sv[wn * 128 + row] = bv; si[wn * 128 + row] = bc;
      }
    }
  }
  __syncthreads();
  if (tid < 128) {
    float v = sv[tid]; int ii = si[tid];
    float ov = sv[128 + tid]; int oi = si[128 + tid];
    if (ov < v || (ov == v && oi < ii)) { v = ov; ii = oi; }
    partv[(size_t)(m0 + tid) * 64 + bn] = v;
    parti[(size_t)(m0 + tid) * 64 + bn] = ii;
  }
}

// LayerNorm over DH=1024, wave per row, 16 elems/lane
__global__ __launch_bounds__(256)
void k_ln(const u16* __restrict__ X, const float* __restrict__ g,
          const float* __restrict__ b, u16* __restrict__ O) {
  int row = blockIdx.x * 4 + (threadIdx.x >> 6);
  int lane = threadIdx.x & 63;
  const u16* xr = X + (size_t)row * DH + lane * 16;
  uint4 d0 = *(const uint4*)(xr);
  uint4 d1 = *(const uint4*)(xr + 8);
  unsigned int ww[8] = {d0.x, d0.y, d0.z, d0.w, d1.x, d1.y, d1.z, d1.w};
  float v[16];
  #pragma unroll
  for (int i = 0; i < 8; ++i) {
    v[2 * i] = bf2f((u16)(ww[i] & 0xffff));
    v[2 * i + 1] = bf2f((u16)(ww[i] >> 16));
  }
  float s = 0.f;
  #pragma unroll
  for (int i = 0; i < 16; ++i) s += v[i];
  s = wave_sum(s);
  float mean = s * (1.0f / DH);
  float q = 0.f;
  #pragma unroll
  for (int i = 0; i < 16; ++i) { float d = v[i] - mean; q += d * d; }
  q = wave_sum(q);
  float rstd = rsqrtf(q * (1.0f / DH) + 1e-5f);
  int base = lane * 16;
  unsigned int ow[8];
  #pragma unroll
  for (int i = 0; i < 8; ++i) {
    float a0 = (v[2 * i] - mean) * rstd * g[base + 2 * i] + b[base + 2 * i];
    float a1 = (v[2 * i + 1] - mean) * rstd * g[base + 2 * i + 1] + b[base + 2 * i + 1];
    ow[i] = (unsigned int)f2bf(a0) | ((unsigned int)f2bf(a1) << 16);
  }
  uint4 o0 = {ow[0], ow[1], ow[2], ow[3]};
  uint4 o1 = {ow[4], ow[5], ow[6], ow[7]};
  *(uint4*)(O + (size_t)row * DH + lane * 16) = o0;
  *(uint4*)(O + (size_t)row * DH + lane * 16 + 8) = o1;
}

// final argmin over 64 partials/row; per-row loss + idx (no quant write)
__global__ __launch_bounds__(256)
void k_argmin_fin(const float* __restrict__ partv, const int* __restrict__ parti,
                  const float* __restrict__ cb, const u16* __restrict__ zq,
                  float* __restrict__ lossbuf, int* __restrict__ idxbuf) {
  int row = blockIdx.x * 4 + (threadIdx.x >> 6);
  int lane = threadIdx.x & 63;
  float v = partv[(size_t)row * 64 + lane];
  int idx = parti[(size_t)row * 64 + lane];
  #pragma unroll
  for (int m = 1; m < 64; m <<= 1) {
    float ov = __shfl_xor(v, m, 64);
    int oi = __shfl_xor(idx, m, 64);
    if (ov < v || (ov == v && oi < idx)) { v = ov; idx = oi; }
  }
  const float* cr = cb + (size_t)idx * DE;
  const u16* zr = zq + (size_t)row * DE;
  float s = 0.f;
  #pragma unroll
  for (int i = 0; i < DE / 64; ++i) {
    int e = lane + i * 64;
    float d = cr[e] - bf2f(zr[e]);
    s += d * d;
  }
  s = wave_sum(s);
  if (lane == 0) { lossbuf[row] = s; idxbuf[row] = idx; }
}

// out[i] = CBout[idx[i]]  (wave per row; 1280 f32 = 64 lanes x 5 float4)
__global__ __launch_bounds__(256)
void k_gather(const int* __restrict__ idxbuf, const float* __restrict__ tab,
              float* __restrict__ out) {
  int row = blockIdx.x * 4 + (threadIdx.x >> 6);
  int lane = threadIdx.x & 63;
  const float* src = tab + (size_t)idxbuf[row] * DIN;
  float* dst = out + (size_t)row * DIN;
  #pragma unroll
  for (int j = 0; j < 5; ++j) {
    int e = (lane + j * 64) * 4;
    *(float4*)(dst + e) = *(const float4*)(src + e);
  }
}

// single-block reduction of B_SZ per-row losses -> scaled scalar
__global__ __launch_bounds__(256)
void k_fin(const float* __restrict__ lossbuf, float* __restrict__ out) {
  float s = 0.f;
  for (int i = threadIdx.x; i < B_SZ; i += 256) s += lossbuf[i];
  s = wave_sum(s);
  __shared__ float sm[4];
  if ((threadIdx.x & 63) == 0) sm[threadIdx.x >> 6] = s;
  __syncthreads();
  if (threadIdx.x == 0)
    out[0] = 1.25f * (sm[0] + sm[1] + sm[2] + sm[3]) *
             (1.0f / ((float)B_SZ * (float)DE));
}

extern "C" void kernel_launch(void* const* d_in, const int* in_sizes, int n_in,
                              void* d_out, int out_size, void* d_ws, size_t ws_size,
                              hipStream_t stream) {
  const float* x    = (const float*)d_in[0];
  const float* w_in = (const float*)d_in[1];
  const float* b_in = (const float*)d_in[2];
  const float* w_v  = (const float*)d_in[3];
  const float* b_v  = (const float*)d_in[4];
  const float* w_o  = (const float*)d_in[5];
  const float* b_o  = (const float*)d_in[6];
  const float* ln_g = (const float*)d_in[7];
  const float* ln_b = (const float*)d_in[8];
  const float* w1   = (const float*)d_in[9];
  const float* b1   = (const float*)d_in[10];
  const float* w2   = (const float*)d_in[11];
  const float* b2   = (const float*)d_in[12];
  const float* w_cb = (const float*)d_in[13];
  const float* b_cb = (const float*)d_in[14];
  const float* cb   = (const float*)d_in[15];
  const float* w_d1 = (const float*)d_in[16];
  const float* b_d1 = (const float*)d_in[17];
  const float* w_d2 = (const float*)d_in[18];
  const float* b_d2 = (const float*)d_in[19];
  (void)in_sizes; (void)n_in; (void)out_size; (void)ws_size;

  char* ws = (char*)d_ws;
  size_t off = 0;
  auto alloc = [&](size_t n) {
    char* p = ws + off;
    off += (n + 255) & ~(size_t)255;
    return p;
  };
  u16* x_bf = (u16*)alloc((size_t)B_SZ * DIN * 2);  // dead after h0
  u16* winb = (u16*)alloc((size_t)DH * DIN * 2);
  u16* wob  = (u16*)alloc((size_t)DH * DH * 2);
  u16* w1b  = (u16*)alloc((size_t)DH * DH * 2);
  u16* w2b  = (u16*)alloc((size_t)DH * DH * 2);
  u16* wcbb = (u16*)alloc((size_t)DE * DH * 2);
  u16* wd1b = (u16*)alloc((size_t)DH * DE * 2);
  u16* wd2b = (u16*)alloc((size_t)DIN * DH * 2);
  u16* wvob = (u16*)alloc((size_t)DH * DH * 2);     // fused W_vo (bf16)
  u8*  cb8  = (u8*)alloc((size_t)KCB * DE);
  float* cnormE = (float*)alloc((size_t)KCB * 4);
  float* bvo    = (float*)alloc((size_t)DH * 4);
  float* zero4k = (float*)alloc((size_t)DH * 4);
  float* lossbuf = (float*)alloc((size_t)B_SZ * 4);
  u16* S1 = (u16*)alloc((size_t)B_SZ * DH * 2);
  u16* S2 = (u16*)alloc((size_t)B_SZ * DH * 2);
  u16* S3 = (u16*)alloc((size_t)B_SZ * DH * 2);
  u16* zq = (u16*)alloc((size_t)B_SZ * DE * 2);   // z (kept for loss)
  float* partv = (float*)alloc((size_t)B_SZ * 64 * 4);
  int*   parti = (int*)alloc((size_t)B_SZ * 64 * 4);
  u16* cbbf = (u16*)alloc((size_t)KCB * DE * 2);  // codebook bf16
  int* idxbuf = (int*)alloc((size_t)B_SZ * 4);
  u16* wvtb = S3;                 // transposed w_v (bf16), dead before S3 written
  u8*  z8   = (u8*)S2;            // fp8 z; S2 dead when written, dead before CBout
  u16* CBd1 = S1;                 // [8192x1024] bf16; S1 dead after mlp2
  float* CBout = (float*)S2;      // [8192x1280] f32 = 42 MB, spans S2+S3

  dim3 blk(256);
  // x conversion (large) separately; 8 weight/codebook conversions batched.
  k_f2bf<<<dim3(B_SZ * DIN / 1024), blk, 0, stream>>>(x, x_bf, B_SZ * DIN);
  {
    CvtArgs a;
    const float* srcs[8] = {w_in, w_o, w1, w2, w_cb, w_d1, w_d2, cb};
    u16* dsts[8] = {winb, wob, w1b, w2b, wcbb, wd1b, wd2b, cbbf};
    int ns[8] = {DH * DIN, DH * DH, DH * DH, DH * DH, DE * DH, DH * DE,
                 DIN * DH, KCB * DE};
    int c = 0;
    a.cum[0] = 0;
    for (int s = 0; s < 8; ++s) {
      a.src[s] = srcs[s]; a.dst[s] = dsts[s];
      c += ns[s] / 1024;
      a.cum[s + 1] = c;
    }
    k_f2bf_multi<<<dim3(c), blk, 0, stream>>>(a);
  }
  k_trans_bf<<<dim3(32, 32), blk, 0, stream>>>(w_v, wvtb);
  k_bvo<<<dim3(DH / 4), blk, 0, stream>>>(w_o, b_v, b_o, bvo);
  k_cvt_cb8<<<dim3(KCB / 4), blk, 0, stream>>>(cb, cb8, cnormE);
  hipMemsetAsync(zero4k, 0, DH * 4, stream);

#define GG(M, N) dim3(((M) / BM) * ((N) / BN))
  // W_vo = w_o @ w_v  (A = w_o, W[n,k] = w_v[k,n])
  k_gemm<0><<<GG(DH, DH), blk, 0, stream>>>(wob, wvtb, zero4k, nullptr, wvob, nullptr,
                                            DH, DH, DH / BN);
  // h0 = x@w_in^T + b_in
  k_gemm<0><<<GG(B_SZ, DH), blk, 0, stream>>>(x_bf, winb, b_in, nullptr, S1, nullptr,
                                              DH, DIN, DH / BN);
  // attn + h0 = h0@W_vo^T + b_vo + h0
  k_gemm<1><<<GG(B_SZ, DH), blk, 0, stream>>>(S1, wvob, bvo, S1, S3, nullptr,
                                              DH, DH, DH / BN);
  // h1 = LN(attn+h0)
  k_ln<<<dim3(B_SZ / 4), blk, 0, stream>>>(S3, ln_g, ln_b, S1);
  // t = relu(h1@w1^T + b1)
  k_gemm<2><<<GG(B_SZ, DH), blk, 0, stream>>>(S1, w1b, b1, nullptr, S2, nullptr,
                                              DH, DH, DH / BN);
  // h2 = relu(t@w2^T + b2) + h1
  k_gemm<3><<<GG(B_SZ, DH), blk, 0, stream>>>(S2, w2b, b2, S1, S3, nullptr,
                                              DH, DH, DH / BN);
  // z = h2@w_cb^T + b_cb
  k_gemm<0><<<GG(B_SZ, DE), blk, 0, stream>>>(S3, wcbb, b_cb, nullptr, zq, nullptr,
                                              DE, DH, DE / BN);
  // z -> fp8 (x16) into z8 (overlays S2; S2 dead now)
  k_z2fp8<<<dim3(B_SZ * DE / 2048), blk, 0, stream>>>(zq, z8);
  // fp8 distance partials (r7 kernel)
  k_dist8<<<dim3((B_SZ / 128) * (KCB / 128)), blk, 0, stream>>>(z8, cb8, cnormE,
                                                                partv, parti);
  // final argmin + per-row loss + idx
  k_argmin_fin<<<dim3(B_SZ / 4), blk, 0, stream>>>(partv, parti, cb, zq,
                                                   lossbuf, idxbuf);
  // decoder lookup tables on the 8192 codebook rows:
  // CBd1 = relu(cb@w_d1^T + b_d1)   [8192x1024] bf16 (into S1)
  k_gemm<2><<<GG(KCB, DH), blk, 0, stream>>>(cbbf, wd1b, b_d1, nullptr, CBd1, nullptr,
                                             DH, DE, DH / BN);
  // CBout = relu(CBd1@w_d2^T + b_d2) [8192x1280] f32 (into S2+S3)
  k_gemm<4><<<GG(KCB, DIN), blk, 0, stream>>>(CBd1, wd2b, b_d2, nullptr, nullptr,
                                              CBout, DIN, DH, DIN / BN);
  // out = CBout[idx]
  k_gather<<<dim3(B_SZ / 4), blk, 0, stream>>>(idxbuf, CBout, (float*)d_out);
  // loss scalar at d_out[B*DIN]
  k_fin<<<dim3(1), blk, 0, stream>>>(lossbuf, ((float*)d_out) + (size_t)B_SZ * DIN);
#undef GG
}